// Round 9
// baseline (410.121 us; speedup 1.0000x reference)
//
#include <hip/hip_runtime.h>
#include <hip/hip_bf16.h>

// VQ EuclideanCodebook round 9: 2-tile MFMA filter (64 rows/wave, e2 folded
// into acc init, e2 in LDS, interleaved MFMA chains) + thread-per-row exact
// re-rank + count-sort epilogue.

#define NROWS 262144
#define KCODES 1024
#define DDIM 64
#define CAPL 4

typedef __attribute__((ext_vector_type(8)))  short short8;
typedef __attribute__((ext_vector_type(16))) float f32x16;

__device__ __forceinline__ unsigned short f2bf(float f) {
    unsigned u = __float_as_uint(f);
    unsigned r = u + 0x7fffu + ((u >> 16) & 1u);   // RNE to bf16
    return (unsigned short)(r >> 16);
}

// ---- prep: e2 (exact f32, ascending fmaf), E->bf16, max ||e||^2 ----
__global__ __launch_bounds__(256) void vq_prep(
    const float* __restrict__ embed, unsigned short* __restrict__ eb,
    float* __restrict__ e2f, float* __restrict__ enmax2)
{
    const int k = blockIdx.x * 256 + threadIdx.x;   // 0..1023
    const float* er = embed + (size_t)k * DDIM;
    float s = 0.f;
    #pragma unroll
    for (int d = 0; d < DDIM; ++d) { float v = er[d]; s = fmaf(v, v, s); }
    e2f[k] = s;
    #pragma unroll
    for (int d = 0; d < DDIM; ++d) eb[(size_t)k * DDIM + d] = f2bf(er[d]);
    atomicMax((int*)enmax2, __float_as_int(s));     // s >= 0: int-monotone
}

// ---- phase A: 512 rows/block, 2 tiles/wave, E in halves ----
__global__ __launch_bounds__(512, 4) void vq_phaseA(
    const float* __restrict__ x, const unsigned short* __restrict__ eb,
    const float* __restrict__ e2f, const float* __restrict__ enmax2,
    float* __restrict__ out_ind, int* __restrict__ candg, int* __restrict__ cntg,
    int* __restrict__ wl, int* __restrict__ gcount,
    int* __restrict__ wl2, int* __restrict__ gcount2, int* __restrict__ bins_i)
{
    __shared__ __align__(16) unsigned short ebs[32768];   // 64 KB: half of E
    __shared__ float e2L[512];        // -0.5*e2 for the staged half
    __shared__ float norm2L[512];
    __shared__ int   cntL[512];
    __shared__ int   candL[512][CAPL];
    __shared__ int   mcount, mbase, mcount2, mbase2;

    const int t    = threadIdx.x;
    const int lane = t & 63;
    const int wid  = t >> 6;          // 8 waves
    const int lo   = lane & 31;
    const int hi   = lane >> 5;
    const int rowb = blockIdx.x * 512;

    // A fragments for 2 row tiles (row=lane&31, k=16i+8hi+j) + row norms
    short8 af0[4], af1[4];
    {
        const float* xr = x + (size_t)(rowb + wid * 64 + lo) * DDIM;
        float xsq = 0.f;
        #pragma unroll
        for (int i = 0; i < 4; ++i) {
            const float4 a = *reinterpret_cast<const float4*>(xr + 16 * i + 8 * hi);
            const float4 b = *reinterpret_cast<const float4*>(xr + 16 * i + 8 * hi + 4);
            short8 f;
            f[0] = (short)f2bf(a.x); f[1] = (short)f2bf(a.y);
            f[2] = (short)f2bf(a.z); f[3] = (short)f2bf(a.w);
            f[4] = (short)f2bf(b.x); f[5] = (short)f2bf(b.y);
            f[6] = (short)f2bf(b.z); f[7] = (short)f2bf(b.w);
            af0[i] = f;
            xsq = fmaf(a.x, a.x, xsq); xsq = fmaf(a.y, a.y, xsq);
            xsq = fmaf(a.z, a.z, xsq); xsq = fmaf(a.w, a.w, xsq);
            xsq = fmaf(b.x, b.x, xsq); xsq = fmaf(b.y, b.y, xsq);
            xsq = fmaf(b.z, b.z, xsq); xsq = fmaf(b.w, b.w, xsq);
        }
        const float n2 = xsq + __shfl_xor(xsq, 32);
        if (hi == 0) norm2L[wid * 64 + lo] = n2;
    }
    {
        const float* xr = x + (size_t)(rowb + wid * 64 + 32 + lo) * DDIM;
        float xsq = 0.f;
        #pragma unroll
        for (int i = 0; i < 4; ++i) {
            const float4 a = *reinterpret_cast<const float4*>(xr + 16 * i + 8 * hi);
            const float4 b = *reinterpret_cast<const float4*>(xr + 16 * i + 8 * hi + 4);
            short8 f;
            f[0] = (short)f2bf(a.x); f[1] = (short)f2bf(a.y);
            f[2] = (short)f2bf(a.z); f[3] = (short)f2bf(a.w);
            f[4] = (short)f2bf(b.x); f[5] = (short)f2bf(b.y);
            f[6] = (short)f2bf(b.z); f[7] = (short)f2bf(b.w);
            af1[i] = f;
            xsq = fmaf(a.x, a.x, xsq); xsq = fmaf(a.y, a.y, xsq);
            xsq = fmaf(a.z, a.z, xsq); xsq = fmaf(a.w, a.w, xsq);
            xsq = fmaf(b.x, b.x, xsq); xsq = fmaf(b.y, b.y, xsq);
            xsq = fmaf(b.z, b.z, xsq); xsq = fmaf(b.w, b.w, xsq);
        }
        const float n2 = xsq + __shfl_xor(xsq, 32);
        if (hi == 0) norm2L[wid * 64 + 32 + lo] = n2;
    }

    cntL[t] = 0;
    if (t == 0) { mcount = 0; mcount2 = 0; }
    const float en2 = *enmax2;

    f32x16 best0, best1;
    #pragma unroll
    for (int r = 0; r < 16; ++r) { best0[r] = -3.4e38f; best1[r] = -3.4e38f; }

    // stage one 64KB half (16 chunks x 32 codes) swizzled + its -0.5*e2
#define STAGE(H)                                                              \
    _Pragma("unroll")                                                         \
    for (int it = 0; it < 8; ++it) {                                          \
        const int f16  = t + it * 512;                                        \
        const int ch   = f16 >> 8;                                            \
        const int rr_  = f16 & 255;                                           \
        const int code = rr_ >> 3, slot = rr_ & 7;                            \
        const short8 v = *reinterpret_cast<const short8*>(                    \
            eb + (size_t)(H) * 32768 + (size_t)f16 * 8);                      \
        *reinterpret_cast<short8*>((char*)ebs + ch * 4096 + code * 128 +      \
                                   ((slot ^ (code & 7)) << 4)) = v;           \
    }                                                                         \
    e2L[t] = -0.5f * e2f[(H) * 512 + t];

    // one chunk of a sweep: KIND 0 = min-track, 1 = collect
#define CHUNK(ch, KIND, CBASE)                                                \
    {                                                                         \
        short8 bfr[4];                                                        \
        _Pragma("unroll")                                                     \
        for (int i = 0; i < 4; ++i) {                                         \
            const int slot = 2 * i + hi;                                      \
            bfr[i] = *reinterpret_cast<const short8*>(                        \
                (char*)ebs + (ch) * 4096 + lo * 128 + ((slot ^ (lo & 7)) << 4)); \
        }                                                                     \
        const float e2n = e2L[(ch) * 32 + lo];                                \
        f32x16 acc0, acc1;                                                    \
        _Pragma("unroll")                                                     \
        for (int r = 0; r < 16; ++r) { acc0[r] = e2n; acc1[r] = e2n; }        \
        _Pragma("unroll")                                                     \
        for (int i = 0; i < 4; ++i) {                                         \
            acc0 = __builtin_amdgcn_mfma_f32_32x32x16_bf16(af0[i], bfr[i], acc0, 0, 0, 0); \
            acc1 = __builtin_amdgcn_mfma_f32_32x32x16_bf16(af1[i], bfr[i], acc1, 0, 0, 0); \
        }                                                                     \
        if (KIND == 0) {                                                      \
            _Pragma("unroll")                                                 \
            for (int r = 0; r < 16; ++r) {                                    \
                best0[r] = fmaxf(best0[r], acc0[r]);                          \
                best1[r] = fmaxf(best1[r], acc1[r]);                          \
            }                                                                 \
        } else {                                                              \
            _Pragma("unroll")                                                 \
            for (int r = 0; r < 16; ++r) {                                    \
                if (acc0[r] >= best0[r]) {                                    \
                    const int rr = (r & 3) + 8 * (r >> 2) + 4 * hi;           \
                    const int rl = wid * 64 + rr;                             \
                    const int idx = atomicAdd(&cntL[rl], 1);                  \
                    if (idx < CAPL) candL[rl][idx] = (CBASE) + (ch) * 32 + lo;\
                }                                                             \
                if (acc1[r] >= best1[r]) {                                    \
                    const int rr = (r & 3) + 8 * (r >> 2) + 4 * hi;           \
                    const int rl = wid * 64 + 32 + rr;                        \
                    const int idx = atomicAdd(&cntL[rl], 1);                  \
                    if (idx < CAPL) candL[rl][idx] = (CBASE) + (ch) * 32 + lo;\
                }                                                             \
            }                                                                 \
        }                                                                     \
    }

    // ---------- sweep 1 ----------
    STAGE(0)
    __syncthreads();
    #pragma unroll 2
    for (int ch = 0; ch < 16; ++ch) CHUNK(ch, 0, 0)
    __syncthreads();
    STAGE(1)
    __syncthreads();
    #pragma unroll 2
    for (int ch = 0; ch < 16; ++ch) CHUNK(ch, 0, 512)

    // cross-lane max (min dist = max acc) + margin/2 in acc domain
    #pragma unroll
    for (int r = 0; r < 16; ++r) {
        float v0 = best0[r], v1 = best1[r];
        v0 = fmaxf(v0, __shfl_xor(v0, 1));  v1 = fmaxf(v1, __shfl_xor(v1, 1));
        v0 = fmaxf(v0, __shfl_xor(v0, 2));  v1 = fmaxf(v1, __shfl_xor(v1, 2));
        v0 = fmaxf(v0, __shfl_xor(v0, 4));  v1 = fmaxf(v1, __shfl_xor(v1, 4));
        v0 = fmaxf(v0, __shfl_xor(v0, 8));  v1 = fmaxf(v1, __shfl_xor(v1, 8));
        v0 = fmaxf(v0, __shfl_xor(v0, 16)); v1 = fmaxf(v1, __shfl_xor(v1, 16));
        const int rr = (r & 3) + 8 * (r >> 2) + 4 * hi;
        const float m0 = 0.0078125f * sqrtf(norm2L[wid * 64 + rr] * en2) + 5e-5f;
        const float m1 = 0.0078125f * sqrtf(norm2L[wid * 64 + 32 + rr] * en2) + 5e-5f;
        best0[r] = v0 - m0;               // acc-domain threshold
        best1[r] = v1 - m1;
    }

    // ---------- sweep 2: resident half 1 first, then restage half 0 ----------
    #pragma unroll 2
    for (int ch = 0; ch < 16; ++ch) CHUNK(ch, 1, 512)
    __syncthreads();
    STAGE(0)
    __syncthreads();
    #pragma unroll 2
    for (int ch = 0; ch < 16; ++ch) CHUNK(ch, 1, 0)
    __syncthreads();

    // finalize single-candidate rows (+histogram); enqueue multi/overflow rows
    int my = -1, my2 = -1;
    const int c = cntL[t];
    if (c == 1) {
        const int code = candL[t][0];
        out_ind[rowb + t] = (float)code;
        atomicAdd(bins_i + code, 1);
    }
    else if (c <= CAPL)   my  = atomicAdd(&mcount, 1);
    else                  my2 = atomicAdd(&mcount2, 1);
    __syncthreads();
    if (t == 0) { mbase = atomicAdd(gcount, mcount); mbase2 = atomicAdd(gcount2, mcount2); }
    __syncthreads();
    if (my >= 0) {
        const int row = rowb + t;
        wl[mbase + my] = row;
        cntg[row] = c;
        #pragma unroll
        for (int j = 0; j < CAPL; ++j)
            if (j < c) candg[row * CAPL + j] = candL[t][j];
    }
    if (my2 >= 0) wl2[mbase2 + my2] = rowb + t;
#undef STAGE
#undef CHUNK
}

// ---- re-rank 2..4-candidate rows: one THREAD per row (+histogram) ----
__global__ __launch_bounds__(256) void vq_rerank1(
    const float* __restrict__ x, const float* __restrict__ embed,
    const float* __restrict__ e2f, const int* __restrict__ wl,
    const int* __restrict__ gcount, const int* __restrict__ cntg,
    const int* __restrict__ candg, float* __restrict__ out_ind,
    int* __restrict__ bins_i)
{
    const int n = *gcount;
    for (int i = blockIdx.x * 256 + threadIdx.x; i < n; i += gridDim.x * 256) {
        const int row = wl[i];
        float xv[DDIM];
        {
            const float4* xp = reinterpret_cast<const float4*>(x + (size_t)row * DDIM);
            float4 xq[16];
            #pragma unroll
            for (int q = 0; q < 16; ++q) xq[q] = xp[q];      // independent loads (ILP)
            #pragma unroll
            for (int q = 0; q < 16; ++q) {
                xv[q*4+0] = xq[q].x; xv[q*4+1] = xq[q].y;
                xv[q*4+2] = xq[q].z; xv[q*4+3] = xq[q].w;
            }
        }
        float x2 = 0.f;
        #pragma unroll
        for (int d = 0; d < DDIM; ++d) x2 = fmaf(xv[d], xv[d], x2);

        const int c = cntg[row];
        float bv = 3.4e38f; int bk = 0x7fffffff;
        for (int ci = 0; ci < c; ++ci) {
            const int k = candg[row * CAPL + ci];
            const float4* ep = reinterpret_cast<const float4*>(embed + (size_t)k * DDIM);
            float dot = 0.f;
            #pragma unroll
            for (int q = 0; q < 16; ++q) {
                const float4 e4 = ep[q];
                dot = fmaf(xv[q*4+0], e4.x, dot);
                dot = fmaf(xv[q*4+1], e4.y, dot);
                dot = fmaf(xv[q*4+2], e4.z, dot);
                dot = fmaf(xv[q*4+3], e4.w, dot);
            }
            const float dist = (x2 - 2.0f * dot) + e2f[k];
            if (dist < bv || (dist == bv && k < bk)) { bv = dist; bk = k; }
        }
        out_ind[row] = (float)bk;
        atomicAdd(bins_i + bk, 1);
    }
}

// ---- overflow rows: one WAVE per row, exact full scan (+histogram) ----
__global__ __launch_bounds__(256) void vq_rerank2(
    const float* __restrict__ x, const float* __restrict__ embed,
    const float* __restrict__ e2f, const int* __restrict__ wl2,
    const int* __restrict__ gcount2, float* __restrict__ out_ind,
    int* __restrict__ bins_i)
{
    const int t    = threadIdx.x;
    const int lane = t & 63;
    const int gw   = (blockIdx.x * 256 + t) >> 6;
    const int nw   = (gridDim.x * 256) >> 6;
    const int n    = *gcount2;

    for (int e = gw; e < n; e += nw) {
        const int row = wl2[e];
        float xv[DDIM];
        {
            const float4* xp = reinterpret_cast<const float4*>(x + (size_t)row * DDIM);
            #pragma unroll
            for (int q = 0; q < 16; ++q) {
                const float4 v = xp[q];
                xv[q*4+0] = v.x; xv[q*4+1] = v.y; xv[q*4+2] = v.z; xv[q*4+3] = v.w;
            }
        }
        float x2 = 0.f;
        #pragma unroll
        for (int d = 0; d < DDIM; ++d) x2 = fmaf(xv[d], xv[d], x2);

        float bv = 3.4e38f; int bk = 0x7fffffff;
        for (int k = lane; k < KCODES; k += 64) {
            const float* er = embed + (size_t)k * DDIM;
            float dot = 0.f;
            #pragma unroll
            for (int d = 0; d < DDIM; ++d) dot = fmaf(xv[d], er[d], dot);
            const float dist = (x2 - 2.0f * dot) + e2f[k];
            if (dist < bv) { bv = dist; bk = k; }
        }
        #pragma unroll
        for (int s = 1; s < 64; s <<= 1) {
            const float ov = __shfl_xor(bv, s);
            const int   ok = __shfl_xor(bk, s);
            if (ov < bv || (ov == bv && ok < bk)) { bv = ov; bk = ok; }
        }
        if (lane == 0) { out_ind[row] = (float)bk; atomicAdd(bins_i + bk, 1); }
    }
}

// ---- exclusive prefix over bins -> offs, cursor ----
__global__ __launch_bounds__(1024) void vq_prefix(
    const int* __restrict__ bins_i, int* __restrict__ offs, int* __restrict__ cursor)
{
    __shared__ int s[KCODES];
    const int t = threadIdx.x;
    const int b = bins_i[t];
    s[t] = b;
    __syncthreads();
    for (int d = 1; d < KCODES; d <<= 1) {
        const int v = (t >= d) ? s[t - d] : 0;
        __syncthreads();
        s[t] += v;
        __syncthreads();
    }
    const int excl = s[t] - b;
    offs[t] = excl;
    cursor[t] = excl;
}

// ---- scatter packed (code<<20)|row into code-sorted order ----
__global__ __launch_bounds__(256) void vq_scatter(
    const float* __restrict__ out_ind, int* __restrict__ cursor, int* __restrict__ sorted)
{
    const int row  = blockIdx.x * 256 + threadIdx.x;
    const int code = (int)out_ind[row];
    const int pos  = atomicAdd(cursor + code, 1);
    sorted[pos] = (code << 20) | row;
}

// ---- balanced segmented reduce: 64 positions per wave, boundary atomics ----
__global__ __launch_bounds__(256) void vq_reduce(
    const float* __restrict__ x, const int* __restrict__ sorted,
    float* __restrict__ esum)
{
    const int t = threadIdx.x, lane = t & 63, w = t >> 6;
    const int p0 = (blockIdx.x * 4 + w) * 64;     // this wave's 64 positions

    int cur = sorted[p0] >> 20;
    float acc = 0.f;
    #pragma unroll 4
    for (int i = 0; i < 64; i += 4) {
        const int4 e4 = *reinterpret_cast<const int4*>(sorted + p0 + i);
        const float v0 = x[(size_t)(e4.x & 0xFFFFF) * DDIM + lane];
        const float v1 = x[(size_t)(e4.y & 0xFFFFF) * DDIM + lane];
        const float v2 = x[(size_t)(e4.z & 0xFFFFF) * DDIM + lane];
        const float v3 = x[(size_t)(e4.w & 0xFFFFF) * DDIM + lane];
        const int c0 = e4.x >> 20, c1 = e4.y >> 20, c2 = e4.z >> 20, c3 = e4.w >> 20;
        if (c0 != cur) { unsafeAtomicAdd(esum + cur * DDIM + lane, acc); acc = 0.f; cur = c0; }
        acc += v0;
        if (c1 != cur) { unsafeAtomicAdd(esum + cur * DDIM + lane, acc); acc = 0.f; cur = c1; }
        acc += v1;
        if (c2 != cur) { unsafeAtomicAdd(esum + cur * DDIM + lane, acc); acc = 0.f; cur = c2; }
        acc += v2;
        if (c3 != cur) { unsafeAtomicAdd(esum + cur * DDIM + lane, acc); acc = 0.f; cur = c3; }
        acc += v3;
    }
    unsafeAtomicAdd(esum + cur * DDIM + lane, acc);
}

// ---- finalize: EMA + Laplace smoothing ----
__global__ __launch_bounds__(1024) void vq_finalize(
    const float* __restrict__ cluster_size, const float* __restrict__ embed_avg,
    const int* __restrict__ bins_i, float* __restrict__ out_cs,
    float* __restrict__ out_eavg, float* __restrict__ out_enorm)
{
    __shared__ float red[KCODES];
    __shared__ float css[KCODES];
    const int t = threadIdx.x;

    const float csn = cluster_size[t] * 0.1f + (float)bins_i[t] * 0.9f;
    red[t] = csn;
    __syncthreads();
    for (int s = 512; s > 0; s >>= 1) {
        if (t < s) red[t] += red[t + s];
        __syncthreads();
    }
    const float n = red[0];
    out_cs[t] = csn;
    css[t] = (csn + 1e-5f) / (n + (float)(KCODES * 1e-5)) * n;
    __syncthreads();

    #pragma unroll
    for (int i = 0; i < 16; ++i) {
        const int f4 = t + i * 1024;
        const int k  = f4 >> 4;
        const float4 ea = reinterpret_cast<const float4*>(embed_avg)[f4];
        const float4 su = reinterpret_cast<const float4*>(out_eavg)[f4];
        const float  cc = css[k];
        float4 ean, en;
        ean.x = ea.x * 0.1f + su.x * 0.9f; en.x = ean.x / cc;
        ean.y = ea.y * 0.1f + su.y * 0.9f; en.y = ean.y / cc;
        ean.z = ea.z * 0.1f + su.z * 0.9f; en.z = ean.z / cc;
        ean.w = ea.w * 0.1f + su.w * 0.9f; en.w = ean.w / cc;
        reinterpret_cast<float4*>(out_eavg)[f4]  = ean;
        reinterpret_cast<float4*>(out_enorm)[f4] = en;
    }
}

// ---- quantize gather (runs last; out_q region doubles as scratch before) ----
__global__ __launch_bounds__(256) void vq_quant(
    const float* __restrict__ out_ind, const float* __restrict__ embed,
    float* __restrict__ out_q)
{
    __shared__ int inds[256];
    const int t = threadIdx.x;
    const int row0 = blockIdx.x * 256;
    inds[t] = (int)out_ind[row0 + t];
    __syncthreads();
    #pragma unroll
    for (int i = 0; i < 16; ++i) {
        const int f = t + i * 256;
        const int r = f >> 4, dq = f & 15;
        const int code = inds[r];
        const float4 ev = *reinterpret_cast<const float4*>(
            embed + (size_t)code * DDIM + dq * 4);
        *reinterpret_cast<float4*>(out_q + (size_t)(row0 + r) * DDIM + dq * 4) = ev;
    }
}

extern "C" void kernel_launch(void* const* d_in, const int* in_sizes, int n_in,
                              void* d_out, int out_size, void* d_ws, size_t ws_size,
                              hipStream_t stream)
{
    const float* x            = (const float*)d_in[0];
    const float* embed        = (const float*)d_in[1];
    const float* cluster_size = (const float*)d_in[2];
    const float* embed_avg    = (const float*)d_in[3];

    float* out      = (float*)d_out;
    float* out_q    = out;                                   // N*D (scratch until vq_quant)
    float* out_ind  = out_q + (size_t)NROWS * DDIM;          // N
    float* out_cs   = out_ind + NROWS;                       // K
    float* out_eavg = out_cs + KCODES;                       // K*D (embed_sum accum, then EMA)
    float* out_en   = out_eavg + (size_t)KCODES * DDIM;      // K*D (eb/e2f scratch, then enorm)

    unsigned short* eb = (unsigned short*)out_en;            // K*D bf16 = 128 KB
    float* e2f = out_en + 32768;                             // K floats

    int* S      = (int*)out_q;                               // scratch inside out_q
    int* candg  = S;                                         // N*4
    int* cntg   = S + 1048576;                               // N
    int* wl     = S + 1310720;                               // N
    int* wl2    = S + 1572864;                               // N
    int* sorted = S + 1835008;                               // N
    int* bins_i = S + 2097152;                               // K
    int* gcount = bins_i + KCODES;                           // 1
    int* gcount2= gcount + 1;                                // 1
    float* enmax2 = (float*)(gcount2 + 1);                   // 1
    int* offs   = gcount2 + 2;                               // K
    int* cursor = offs + KCODES;                             // K

    // one contiguous zero: bins_i + gcount + gcount2 + enmax2
    hipMemsetAsync(bins_i, 0, (KCODES + 3) * sizeof(int), stream);
    hipMemsetAsync(out_eavg, 0, (size_t)KCODES * DDIM * sizeof(float), stream);

    vq_prep    <<<KCODES / 256, 256, 0, stream>>>(embed, eb, e2f, enmax2);
    vq_phaseA  <<<NROWS / 512, 512, 0, stream>>>(x, eb, e2f, enmax2, out_ind,
                                                 candg, cntg, wl, gcount,
                                                 wl2, gcount2, bins_i);
    vq_rerank1 <<<512, 256, 0, stream>>>(x, embed, e2f, wl, gcount, cntg, candg,
                                         out_ind, bins_i);
    vq_rerank2 <<<128, 256, 0, stream>>>(x, embed, e2f, wl2, gcount2, out_ind, bins_i);
    vq_prefix  <<<1, 1024, 0, stream>>>(bins_i, offs, cursor);
    vq_scatter <<<NROWS / 256, 256, 0, stream>>>(out_ind, cursor, sorted);
    vq_reduce  <<<NROWS / 256, 256, 0, stream>>>(x, sorted, out_eavg);
    vq_finalize<<<1, 1024, 0, stream>>>(cluster_size, embed_avg, bins_i,
                                        out_cs, out_eavg, out_en);
    vq_quant   <<<NROWS / 256, 256, 0, stream>>>(out_ind, embed, out_q);
}

// Round 10
// 334.578 us; speedup vs baseline: 1.2258x; 1.2258x over previous
//
#include <hip/hip_runtime.h>
#include <hip/hip_bf16.h>

// VQ EuclideanCodebook round 10: 16x16x32 MFMA filter (4-reg accumulators ->
// <=64-reg class -> 32 waves/CU), 2 row-tiles/wave, quarter-staged E with
// compile-time ds_read offsets, acc-domain margin; thread-per-row exact
// re-rank + count-sort epilogue (all validated in rounds 5-9).

#define NROWS 262144
#define KCODES 1024
#define DDIM 64
#define CAPL 4

typedef __attribute__((ext_vector_type(8))) short short8;
typedef __attribute__((ext_vector_type(4))) float f32x4;

__device__ __forceinline__ unsigned short f2bf(float f) {
    unsigned u = __float_as_uint(f);
    unsigned r = u + 0x7fffu + ((u >> 16) & 1u);   // RNE to bf16
    return (unsigned short)(r >> 16);
}

// ---- prep: e2 (exact f32, ascending fmaf), E->bf16, max ||e||^2 ----
__global__ __launch_bounds__(256) void vq_prep(
    const float* __restrict__ embed, unsigned short* __restrict__ eb,
    float* __restrict__ e2f, float* __restrict__ enmax2)
{
    const int k = blockIdx.x * 256 + threadIdx.x;   // 0..1023
    const float* er = embed + (size_t)k * DDIM;
    float s = 0.f;
    #pragma unroll
    for (int d = 0; d < DDIM; ++d) { float v = er[d]; s = fmaf(v, v, s); }
    e2f[k] = s;
    #pragma unroll
    for (int d = 0; d < DDIM; ++d) eb[(size_t)k * DDIM + d] = f2bf(er[d]);
    atomicMax((int*)enmax2, __float_as_int(s));     // s >= 0: int-monotone
}

// ---- phase A: 256 rows/block (8 waves x 32 rows), E staged in quarters ----
__global__ __launch_bounds__(512) void vq_phaseA(
    const float* __restrict__ x, const unsigned short* __restrict__ eb,
    const float* __restrict__ e2f, const float* __restrict__ enmax2,
    float* __restrict__ out_ind, int* __restrict__ candg, int* __restrict__ cntg,
    int* __restrict__ wl, int* __restrict__ gcount,
    int* __restrict__ wl2, int* __restrict__ gcount2, int* __restrict__ bins_i)
{
    __shared__ __align__(16) unsigned short ebs[16384];   // 32 KB: quarter of E
    __shared__ float e2L[256];        // -0.5*e2 of the staged quarter
    __shared__ float norm2L[256];
    __shared__ int   cntL[256];
    __shared__ int   candL[256][CAPL];
    __shared__ int   mcount, mbase, mcount2, mbase2;

    const int t    = threadIdx.x;
    const int lane = t & 63;
    const int wid  = t >> 6;          // 8 waves, 32 rows each
    const int col  = lane & 15;       // 16x16 A-row / B-col / C-col
    const int q    = lane >> 4;       // 0..3 (k-quarter / C-row group)
    const int rowb = blockIdx.x * 256;
    const int r0   = wid * 32;        // local row base of this wave

    // A fragments (row=lane&15, k = m*32 + 8*q + j) for 2 tiles + row norms
    short8 a0[2], a1[2];
    {
        const float* xr = x + (size_t)(rowb + r0 + col) * DDIM;
        float s = 0.f;
        #pragma unroll
        for (int m = 0; m < 2; ++m) {
            const float4 u = *reinterpret_cast<const float4*>(xr + m * 32 + 8 * q);
            const float4 v = *reinterpret_cast<const float4*>(xr + m * 32 + 8 * q + 4);
            short8 f;
            f[0] = (short)f2bf(u.x); f[1] = (short)f2bf(u.y);
            f[2] = (short)f2bf(u.z); f[3] = (short)f2bf(u.w);
            f[4] = (short)f2bf(v.x); f[5] = (short)f2bf(v.y);
            f[6] = (short)f2bf(v.z); f[7] = (short)f2bf(v.w);
            a0[m] = f;
            s = fmaf(u.x, u.x, s); s = fmaf(u.y, u.y, s);
            s = fmaf(u.z, u.z, s); s = fmaf(u.w, u.w, s);
            s = fmaf(v.x, v.x, s); s = fmaf(v.y, v.y, s);
            s = fmaf(v.z, v.z, s); s = fmaf(v.w, v.w, s);
        }
        s += __shfl_xor(s, 16); s += __shfl_xor(s, 32);   // sum over q-groups
        if (lane < 16) norm2L[r0 + lane] = s;
    }
    {
        const float* xr = x + (size_t)(rowb + r0 + 16 + col) * DDIM;
        float s = 0.f;
        #pragma unroll
        for (int m = 0; m < 2; ++m) {
            const float4 u = *reinterpret_cast<const float4*>(xr + m * 32 + 8 * q);
            const float4 v = *reinterpret_cast<const float4*>(xr + m * 32 + 8 * q + 4);
            short8 f;
            f[0] = (short)f2bf(u.x); f[1] = (short)f2bf(u.y);
            f[2] = (short)f2bf(u.z); f[3] = (short)f2bf(u.w);
            f[4] = (short)f2bf(v.x); f[5] = (short)f2bf(v.y);
            f[6] = (short)f2bf(v.z); f[7] = (short)f2bf(v.w);
            a1[m] = f;
            s = fmaf(u.x, u.x, s); s = fmaf(u.y, u.y, s);
            s = fmaf(u.z, u.z, s); s = fmaf(u.w, u.w, s);
            s = fmaf(v.x, v.x, s); s = fmaf(v.y, v.y, s);
            s = fmaf(v.z, v.z, s); s = fmaf(v.w, v.w, s);
        }
        s += __shfl_xor(s, 16); s += __shfl_xor(s, 32);
        if (lane < 16) norm2L[r0 + 16 + lane] = s;
    }

    if (t < 256) cntL[t] = 0;
    if (t == 0) { mcount = 0; mcount2 = 0; }
    const float en2 = *enmax2;

    // per-lane swizzled LDS byte offsets for the two K-halves (loop-invariant)
    const int off0 = col * 128 + ((q       ^ (col & 7)) << 4);
    const int off1 = col * 128 + (((4 + q) ^ (col & 7)) << 4);

    f32x4 best0, best1;
    #pragma unroll
    for (int r = 0; r < 4; ++r) { best0[r] = -3.4e38f; best1[r] = -3.4e38f; }

    // stage one 32KB quarter (256 codes) swizzled + its -0.5*e2
#define STAGE16(P)                                                            \
    _Pragma("unroll")                                                         \
    for (int it = 0; it < 4; ++it) {                                          \
        const int f16 = t + it * 512;                                         \
        const int cp  = f16 >> 3, slot = f16 & 7;                             \
        const short8 v = *reinterpret_cast<const short8*>(                    \
            eb + (size_t)(P) * 16384 + (size_t)f16 * 8);                      \
        *reinterpret_cast<short8*>((char*)ebs + (cp >> 5) * 4096 +            \
            (cp & 31) * 128 + ((slot ^ (cp & 7)) << 4)) = v;                  \
    }                                                                         \
    if (t < 256) e2L[t] = -0.5f * e2f[(P) * 256 + t];

    // 16 chunks of 16 codes over the staged quarter; KIND 0=min, 1=collect
#define CHUNKS(P, KIND)                                                       \
    _Pragma("unroll")                                                         \
    for (int ch = 0; ch < 16; ++ch) {                                         \
        const short8 b0 = *reinterpret_cast<const short8*>(                   \
            (char*)ebs + ch * 2048 + off0);                                   \
        const short8 b1 = *reinterpret_cast<const short8*>(                   \
            (char*)ebs + ch * 2048 + off1);                                   \
        const float e2n = e2L[ch * 16 + col];                                 \
        f32x4 acc0, acc1;                                                     \
        acc0[0] = e2n; acc0[1] = e2n; acc0[2] = e2n; acc0[3] = e2n;           \
        acc1 = acc0;                                                          \
        acc0 = __builtin_amdgcn_mfma_f32_16x16x32_bf16(a0[0], b0, acc0, 0, 0, 0); \
        acc1 = __builtin_amdgcn_mfma_f32_16x16x32_bf16(a1[0], b0, acc1, 0, 0, 0); \
        acc0 = __builtin_amdgcn_mfma_f32_16x16x32_bf16(a0[1], b1, acc0, 0, 0, 0); \
        acc1 = __builtin_amdgcn_mfma_f32_16x16x32_bf16(a1[1], b1, acc1, 0, 0, 0); \
        if (KIND == 0) {                                                      \
            _Pragma("unroll")                                                 \
            for (int r = 0; r < 4; ++r) {                                     \
                best0[r] = fmaxf(best0[r], acc0[r]);                          \
                best1[r] = fmaxf(best1[r], acc1[r]);                          \
            }                                                                 \
        } else {                                                              \
            _Pragma("unroll")                                                 \
            for (int r = 0; r < 4; ++r) {                                     \
                if (acc0[r] >= best0[r]) {                                    \
                    const int rl = r0 + q * 4 + r;                            \
                    const int idx = atomicAdd(&cntL[rl], 1);                  \
                    if (idx < CAPL) candL[rl][idx] = (P) * 256 + ch * 16 + col; \
                }                                                             \
                if (acc1[r] >= best1[r]) {                                    \
                    const int rl = r0 + 16 + q * 4 + r;                       \
                    const int idx = atomicAdd(&cntL[rl], 1);                  \
                    if (idx < CAPL) candL[rl][idx] = (P) * 256 + ch * 16 + col; \
                }                                                             \
            }                                                                 \
        }                                                                     \
    }

    // ---------- sweep 1: running max of acc = dot - 0.5*e2 ----------
    for (int p = 0; p < 4; ++p) {
        __syncthreads();
        STAGE16(p)
        __syncthreads();
        CHUNKS(p, 0)
    }

    // per-row max over 16 cols + acc-domain margin (dist margin / 2)
    #pragma unroll
    for (int r = 0; r < 4; ++r) {
        float v0 = best0[r], v1 = best1[r];
        v0 = fmaxf(v0, __shfl_xor(v0, 1));  v1 = fmaxf(v1, __shfl_xor(v1, 1));
        v0 = fmaxf(v0, __shfl_xor(v0, 2));  v1 = fmaxf(v1, __shfl_xor(v1, 2));
        v0 = fmaxf(v0, __shfl_xor(v0, 4));  v1 = fmaxf(v1, __shfl_xor(v1, 4));
        v0 = fmaxf(v0, __shfl_xor(v0, 8));  v1 = fmaxf(v1, __shfl_xor(v1, 8));
        const int lr = q * 4 + r;
        const float m0 = 0.0078125f * sqrtf(norm2L[r0 + lr] * en2) + 5e-5f;
        const float m1 = 0.0078125f * sqrtf(norm2L[r0 + 16 + lr] * en2) + 5e-5f;
        best0[r] = v0 - m0;               // acc-domain threshold
        best1[r] = v1 - m1;
    }

    // ---------- sweep 2: resident quarter 3 first, then 0,1,2 ----------
    CHUNKS(3, 1)
    for (int p = 0; p < 3; ++p) {
        __syncthreads();
        STAGE16(p)
        __syncthreads();
        CHUNKS(p, 1)
    }
    __syncthreads();

    // finalize single-candidate rows (+histogram); enqueue multi/overflow rows
    int my = -1, my2 = -1, c = 0;
    if (t < 256) {
        c = cntL[t];
        if (c == 1) {
            const int code = candL[t][0];
            out_ind[rowb + t] = (float)code;
            atomicAdd(bins_i + code, 1);
        }
        else if (c <= CAPL)   my  = atomicAdd(&mcount, 1);
        else                  my2 = atomicAdd(&mcount2, 1);
    }
    __syncthreads();
    if (t == 0) { mbase = atomicAdd(gcount, mcount); mbase2 = atomicAdd(gcount2, mcount2); }
    __syncthreads();
    if (my >= 0) {
        const int row = rowb + t;
        wl[mbase + my] = row;
        cntg[row] = c;
        #pragma unroll
        for (int j = 0; j < CAPL; ++j)
            if (j < c) candg[row * CAPL + j] = candL[t][j];
    }
    if (my2 >= 0) wl2[mbase2 + my2] = rowb + t;
#undef STAGE16
#undef CHUNKS
}

// ---- re-rank 2..4-candidate rows: one THREAD per row (+histogram) ----
__global__ __launch_bounds__(256) void vq_rerank1(
    const float* __restrict__ x, const float* __restrict__ embed,
    const float* __restrict__ e2f, const int* __restrict__ wl,
    const int* __restrict__ gcount, const int* __restrict__ cntg,
    const int* __restrict__ candg, float* __restrict__ out_ind,
    int* __restrict__ bins_i)
{
    const int n = *gcount;
    for (int i = blockIdx.x * 256 + threadIdx.x; i < n; i += gridDim.x * 256) {
        const int row = wl[i];
        float xv[DDIM];
        {
            const float4* xp = reinterpret_cast<const float4*>(x + (size_t)row * DDIM);
            float4 xq[16];
            #pragma unroll
            for (int qq = 0; qq < 16; ++qq) xq[qq] = xp[qq];   // independent loads
            #pragma unroll
            for (int qq = 0; qq < 16; ++qq) {
                xv[qq*4+0] = xq[qq].x; xv[qq*4+1] = xq[qq].y;
                xv[qq*4+2] = xq[qq].z; xv[qq*4+3] = xq[qq].w;
            }
        }
        float x2 = 0.f;
        #pragma unroll
        for (int d = 0; d < DDIM; ++d) x2 = fmaf(xv[d], xv[d], x2);

        const int c = cntg[row];
        float bv = 3.4e38f; int bk = 0x7fffffff;
        for (int ci = 0; ci < c; ++ci) {
            const int k = candg[row * CAPL + ci];
            const float4* ep = reinterpret_cast<const float4*>(embed + (size_t)k * DDIM);
            float dot = 0.f;
            #pragma unroll
            for (int qq = 0; qq < 16; ++qq) {
                const float4 e4 = ep[qq];
                dot = fmaf(xv[qq*4+0], e4.x, dot);
                dot = fmaf(xv[qq*4+1], e4.y, dot);
                dot = fmaf(xv[qq*4+2], e4.z, dot);
                dot = fmaf(xv[qq*4+3], e4.w, dot);
            }
            const float dist = (x2 - 2.0f * dot) + e2f[k];
            if (dist < bv || (dist == bv && k < bk)) { bv = dist; bk = k; }
        }
        out_ind[row] = (float)bk;
        atomicAdd(bins_i + bk, 1);
    }
}

// ---- overflow rows: one WAVE per row, exact full scan (+histogram) ----
__global__ __launch_bounds__(256) void vq_rerank2(
    const float* __restrict__ x, const float* __restrict__ embed,
    const float* __restrict__ e2f, const int* __restrict__ wl2,
    const int* __restrict__ gcount2, float* __restrict__ out_ind,
    int* __restrict__ bins_i)
{
    const int t    = threadIdx.x;
    const int lane = t & 63;
    const int gw   = (blockIdx.x * 256 + t) >> 6;
    const int nw   = (gridDim.x * 256) >> 6;
    const int n    = *gcount2;

    for (int e = gw; e < n; e += nw) {
        const int row = wl2[e];
        float xv[DDIM];
        {
            const float4* xp = reinterpret_cast<const float4*>(x + (size_t)row * DDIM);
            #pragma unroll
            for (int qq = 0; qq < 16; ++qq) {
                const float4 v = xp[qq];
                xv[qq*4+0] = v.x; xv[qq*4+1] = v.y; xv[qq*4+2] = v.z; xv[qq*4+3] = v.w;
            }
        }
        float x2 = 0.f;
        #pragma unroll
        for (int d = 0; d < DDIM; ++d) x2 = fmaf(xv[d], xv[d], x2);

        float bv = 3.4e38f; int bk = 0x7fffffff;
        for (int k = lane; k < KCODES; k += 64) {
            const float* er = embed + (size_t)k * DDIM;
            float dot = 0.f;
            #pragma unroll
            for (int d = 0; d < DDIM; ++d) dot = fmaf(xv[d], er[d], dot);
            const float dist = (x2 - 2.0f * dot) + e2f[k];
            if (dist < bv) { bv = dist; bk = k; }
        }
        #pragma unroll
        for (int s = 1; s < 64; s <<= 1) {
            const float ov = __shfl_xor(bv, s);
            const int   ok = __shfl_xor(bk, s);
            if (ov < bv || (ov == bv && ok < bk)) { bv = ov; bk = ok; }
        }
        if (lane == 0) { out_ind[row] = (float)bk; atomicAdd(bins_i + bk, 1); }
    }
}

// ---- exclusive prefix over bins -> offs, cursor ----
__global__ __launch_bounds__(1024) void vq_prefix(
    const int* __restrict__ bins_i, int* __restrict__ offs, int* __restrict__ cursor)
{
    __shared__ int s[KCODES];
    const int t = threadIdx.x;
    const int b = bins_i[t];
    s[t] = b;
    __syncthreads();
    for (int d = 1; d < KCODES; d <<= 1) {
        const int v = (t >= d) ? s[t - d] : 0;
        __syncthreads();
        s[t] += v;
        __syncthreads();
    }
    const int excl = s[t] - b;
    offs[t] = excl;
    cursor[t] = excl;
}

// ---- scatter packed (code<<20)|row into code-sorted order ----
__global__ __launch_bounds__(256) void vq_scatter(
    const float* __restrict__ out_ind, int* __restrict__ cursor, int* __restrict__ sorted)
{
    const int row  = blockIdx.x * 256 + threadIdx.x;
    const int code = (int)out_ind[row];
    const int pos  = atomicAdd(cursor + code, 1);
    sorted[pos] = (code << 20) | row;
}

// ---- balanced segmented reduce: 64 positions per wave, boundary atomics ----
__global__ __launch_bounds__(256) void vq_reduce(
    const float* __restrict__ x, const int* __restrict__ sorted,
    float* __restrict__ esum)
{
    const int t = threadIdx.x, lane = t & 63, w = t >> 6;
    const int p0 = (blockIdx.x * 4 + w) * 64;     // this wave's 64 positions

    int cur = sorted[p0] >> 20;
    float acc = 0.f;
    #pragma unroll 4
    for (int i = 0; i < 64; i += 4) {
        const int4 e4 = *reinterpret_cast<const int4*>(sorted + p0 + i);
        const float v0 = x[(size_t)(e4.x & 0xFFFFF) * DDIM + lane];
        const float v1 = x[(size_t)(e4.y & 0xFFFFF) * DDIM + lane];
        const float v2 = x[(size_t)(e4.z & 0xFFFFF) * DDIM + lane];
        const float v3 = x[(size_t)(e4.w & 0xFFFFF) * DDIM + lane];
        const int c0 = e4.x >> 20, c1 = e4.y >> 20, c2 = e4.z >> 20, c3 = e4.w >> 20;
        if (c0 != cur) { unsafeAtomicAdd(esum + cur * DDIM + lane, acc); acc = 0.f; cur = c0; }
        acc += v0;
        if (c1 != cur) { unsafeAtomicAdd(esum + cur * DDIM + lane, acc); acc = 0.f; cur = c1; }
        acc += v1;
        if (c2 != cur) { unsafeAtomicAdd(esum + cur * DDIM + lane, acc); acc = 0.f; cur = c2; }
        acc += v2;
        if (c3 != cur) { unsafeAtomicAdd(esum + cur * DDIM + lane, acc); acc = 0.f; cur = c3; }
        acc += v3;
    }
    unsafeAtomicAdd(esum + cur * DDIM + lane, acc);
}

// ---- finalize: EMA + Laplace smoothing ----
__global__ __launch_bounds__(1024) void vq_finalize(
    const float* __restrict__ cluster_size, const float* __restrict__ embed_avg,
    const int* __restrict__ bins_i, float* __restrict__ out_cs,
    float* __restrict__ out_eavg, float* __restrict__ out_enorm)
{
    __shared__ float red[KCODES];
    __shared__ float css[KCODES];
    const int t = threadIdx.x;

    const float csn = cluster_size[t] * 0.1f + (float)bins_i[t] * 0.9f;
    red[t] = csn;
    __syncthreads();
    for (int s = 512; s > 0; s >>= 1) {
        if (t < s) red[t] += red[t + s];
        __syncthreads();
    }
    const float n = red[0];
    out_cs[t] = csn;
    css[t] = (csn + 1e-5f) / (n + (float)(KCODES * 1e-5)) * n;
    __syncthreads();

    #pragma unroll
    for (int i = 0; i < 16; ++i) {
        const int f4 = t + i * 1024;
        const int k  = f4 >> 4;
        const float4 ea = reinterpret_cast<const float4*>(embed_avg)[f4];
        const float4 su = reinterpret_cast<const float4*>(out_eavg)[f4];
        const float  cc = css[k];
        float4 ean, en;
        ean.x = ea.x * 0.1f + su.x * 0.9f; en.x = ean.x / cc;
        ean.y = ea.y * 0.1f + su.y * 0.9f; en.y = ean.y / cc;
        ean.z = ea.z * 0.1f + su.z * 0.9f; en.z = ean.z / cc;
        ean.w = ea.w * 0.1f + su.w * 0.9f; en.w = ean.w / cc;
        reinterpret_cast<float4*>(out_eavg)[f4]  = ean;
        reinterpret_cast<float4*>(out_enorm)[f4] = en;
    }
}

// ---- quantize gather (runs last; out_q region doubles as scratch before) ----
__global__ __launch_bounds__(256) void vq_quant(
    const float* __restrict__ out_ind, const float* __restrict__ embed,
    float* __restrict__ out_q)
{
    __shared__ int inds[256];
    const int t = threadIdx.x;
    const int row0 = blockIdx.x * 256;
    inds[t] = (int)out_ind[row0 + t];
    __syncthreads();
    #pragma unroll
    for (int i = 0; i < 16; ++i) {
        const int f = t + i * 256;
        const int r = f >> 4, dq = f & 15;
        const int code = inds[r];
        const float4 ev = *reinterpret_cast<const float4*>(
            embed + (size_t)code * DDIM + dq * 4);
        *reinterpret_cast<float4*>(out_q + (size_t)(row0 + r) * DDIM + dq * 4) = ev;
    }
}

extern "C" void kernel_launch(void* const* d_in, const int* in_sizes, int n_in,
                              void* d_out, int out_size, void* d_ws, size_t ws_size,
                              hipStream_t stream)
{
    const float* x            = (const float*)d_in[0];
    const float* embed        = (const float*)d_in[1];
    const float* cluster_size = (const float*)d_in[2];
    const float* embed_avg    = (const float*)d_in[3];

    float* out      = (float*)d_out;
    float* out_q    = out;                                   // N*D (scratch until vq_quant)
    float* out_ind  = out_q + (size_t)NROWS * DDIM;          // N
    float* out_cs   = out_ind + NROWS;                       // K
    float* out_eavg = out_cs + KCODES;                       // K*D (embed_sum accum, then EMA)
    float* out_en   = out_eavg + (size_t)KCODES * DDIM;      // K*D (eb/e2f scratch, then enorm)

    unsigned short* eb = (unsigned short*)out_en;            // K*D bf16 = 128 KB
    float* e2f = out_en + 32768;                             // K floats

    int* S      = (int*)out_q;                               // scratch inside out_q
    int* candg  = S;                                         // N*4
    int* cntg   = S + 1048576;                               // N
    int* wl     = S + 1310720;                               // N
    int* wl2    = S + 1572864;                               // N
    int* sorted = S + 1835008;                               // N
    int* bins_i = S + 2097152;                               // K
    int* gcount = bins_i + KCODES;                           // 1
    int* gcount2= gcount + 1;                                // 1
    float* enmax2 = (float*)(gcount2 + 1);                   // 1
    int* offs   = gcount2 + 2;                               // K
    int* cursor = offs + KCODES;                             // K

    hipMemsetAsync(bins_i, 0, (KCODES + 3) * sizeof(int), stream);
    hipMemsetAsync(out_eavg, 0, (size_t)KCODES * DDIM * sizeof(float), stream);

    vq_prep    <<<KCODES / 256, 256, 0, stream>>>(embed, eb, e2f, enmax2);
    vq_phaseA  <<<NROWS / 256, 512, 0, stream>>>(x, eb, e2f, enmax2, out_ind,
                                                 candg, cntg, wl, gcount,
                                                 wl2, gcount2, bins_i);
    vq_rerank1 <<<512, 256, 0, stream>>>(x, embed, e2f, wl, gcount, cntg, candg,
                                         out_ind, bins_i);
    vq_rerank2 <<<128, 256, 0, stream>>>(x, embed, e2f, wl2, gcount2, out_ind, bins_i);
    vq_prefix  <<<1, 1024, 0, stream>>>(bins_i, offs, cursor);
    vq_scatter <<<NROWS / 256, 256, 0, stream>>>(out_ind, cursor, sorted);
    vq_reduce  <<<NROWS / 256, 256, 0, stream>>>(x, sorted, out_eavg);
    vq_finalize<<<1, 1024, 0, stream>>>(cluster_size, embed_avg, bins_i,
                                        out_cs, out_eavg, out_en);
    vq_quant   <<<NROWS / 256, 256, 0, stream>>>(out_ind, embed, out_q);
}

// Round 11
// 304.038 us; speedup vs baseline: 1.3489x; 1.1004x over previous
//
#include <hip/hip_runtime.h>
#include <hip/hip_bf16.h>

// VQ EuclideanCodebook round 11: 16x16x32 MFMA filter with pre-swizzled E +
// global_load_lds double-buffered quarter pipeline; fused re-rank; count-sort
// epilogue. (Filter/margin/epilogue validated rounds 5-10.)

#define NROWS 262144
#define KCODES 1024
#define DDIM 64
#define CAPL 4

typedef __attribute__((ext_vector_type(8))) short short8;
typedef __attribute__((ext_vector_type(4))) float f32x4;

__device__ __forceinline__ unsigned short f2bf(float f) {
    unsigned u = __float_as_uint(f);
    unsigned r = u + 0x7fffu + ((u >> 16) & 1u);   // RNE to bf16
    return (unsigned short)(r >> 16);
}

// ---- prep: e2 (exact f32), E->bf16 PRE-SWIZZLED, max ||e||^2 ----
// eb byte layout (quarter-local, matches phaseA's ds_read addressing):
//   byte = (k>>8)*32768 + ((k>>5)&7)*4096 + (k&31)*128 + ((slot ^ (k&7))<<4)
__global__ __launch_bounds__(256) void vq_prep(
    const float* __restrict__ embed, unsigned short* __restrict__ eb,
    float* __restrict__ e2f, float* __restrict__ enmax2)
{
    const int k = blockIdx.x * 256 + threadIdx.x;   // 0..1023
    const float* er = embed + (size_t)k * DDIM;
    float s = 0.f;
    #pragma unroll
    for (int d = 0; d < DDIM; ++d) { float v = er[d]; s = fmaf(v, v, s); }
    e2f[k] = s;
    unsigned char* base = (unsigned char*)eb + (k >> 8) * 32768 +
                          ((k >> 5) & 7) * 4096 + (k & 31) * 128;
    #pragma unroll
    for (int sl = 0; sl < 8; ++sl) {
        short8 f;
        #pragma unroll
        for (int j = 0; j < 8; ++j) f[j] = (short)f2bf(er[sl * 8 + j]);
        *reinterpret_cast<short8*>(base + ((sl ^ (k & 7)) << 4)) = f;
    }
    atomicMax((int*)enmax2, __float_as_int(s));     // s >= 0: int-monotone
}

// ---- phase A: 256 rows/block, double-buffered quarters via global_load_lds ----
__global__ __launch_bounds__(512) void vq_phaseA(
    const float* __restrict__ x, const unsigned short* __restrict__ eb,
    const float* __restrict__ e2f, const float* __restrict__ enmax2,
    float* __restrict__ out_ind, int* __restrict__ candg, int* __restrict__ cntg,
    int* __restrict__ wl, int* __restrict__ gcount,
    int* __restrict__ wl2, int* __restrict__ gcount2, int* __restrict__ bins_i)
{
    __shared__ __align__(16) unsigned short ebs0[16384];  // 32 KB quarter buf A
    __shared__ __align__(16) unsigned short ebs1[16384];  // 32 KB quarter buf B
    __shared__ float e2L[KCODES];     // -0.5*e2, all codes (loaded once)
    __shared__ float norm2L[256];
    __shared__ int   cntL[256];
    __shared__ int   candL[256][CAPL];
    __shared__ int   mcount, mbase, mcount2, mbase2;

    const int t    = threadIdx.x;
    const int lane = t & 63;
    const int wid  = t >> 6;          // 8 waves, 32 rows each
    const int col  = lane & 15;       // 16x16 A-row / B-col / C-col
    const int q    = lane >> 4;       // 0..3 (k-quarter / C-row group)
    const int rowb = blockIdx.x * 256;
    const int r0   = wid * 32;

    // issue quarter-0 loads FIRST (linear copy: eb is pre-swizzled)
#define STAGEQ(BUF, P)                                                        \
    {                                                                         \
        const unsigned char* gsrc = (const unsigned char*)eb +                \
            (size_t)(P) * 32768 + t * 16;                                     \
        unsigned char* ldst = (unsigned char*)(BUF) + t * 16;                 \
        _Pragma("unroll")                                                     \
        for (int it = 0; it < 4; ++it)                                        \
            __builtin_amdgcn_global_load_lds(                                 \
                (const __attribute__((address_space(1))) void*)(gsrc + it * 8192), \
                (__attribute__((address_space(3))) void*)(ldst + it * 8192),  \
                16, 0, 0);                                                    \
    }

    STAGEQ(ebs0, 0)

    // A fragments (row=lane&15, k = m*32 + 8*q + j) for 2 tiles + row norms
    short8 a0[2], a1[2];
    {
        const float* xr = x + (size_t)(rowb + r0 + col) * DDIM;
        float s = 0.f;
        #pragma unroll
        for (int m = 0; m < 2; ++m) {
            const float4 u = *reinterpret_cast<const float4*>(xr + m * 32 + 8 * q);
            const float4 v = *reinterpret_cast<const float4*>(xr + m * 32 + 8 * q + 4);
            short8 f;
            f[0] = (short)f2bf(u.x); f[1] = (short)f2bf(u.y);
            f[2] = (short)f2bf(u.z); f[3] = (short)f2bf(u.w);
            f[4] = (short)f2bf(v.x); f[5] = (short)f2bf(v.y);
            f[6] = (short)f2bf(v.z); f[7] = (short)f2bf(v.w);
            a0[m] = f;
            s = fmaf(u.x, u.x, s); s = fmaf(u.y, u.y, s);
            s = fmaf(u.z, u.z, s); s = fmaf(u.w, u.w, s);
            s = fmaf(v.x, v.x, s); s = fmaf(v.y, v.y, s);
            s = fmaf(v.z, v.z, s); s = fmaf(v.w, v.w, s);
        }
        s += __shfl_xor(s, 16); s += __shfl_xor(s, 32);
        if (lane < 16) norm2L[r0 + lane] = s;
    }
    {
        const float* xr = x + (size_t)(rowb + r0 + 16 + col) * DDIM;
        float s = 0.f;
        #pragma unroll
        for (int m = 0; m < 2; ++m) {
            const float4 u = *reinterpret_cast<const float4*>(xr + m * 32 + 8 * q);
            const float4 v = *reinterpret_cast<const float4*>(xr + m * 32 + 8 * q + 4);
            short8 f;
            f[0] = (short)f2bf(u.x); f[1] = (short)f2bf(u.y);
            f[2] = (short)f2bf(u.z); f[3] = (short)f2bf(u.w);
            f[4] = (short)f2bf(v.x); f[5] = (short)f2bf(v.y);
            f[6] = (short)f2bf(v.z); f[7] = (short)f2bf(v.w);
            a1[m] = f;
            s = fmaf(u.x, u.x, s); s = fmaf(u.y, u.y, s);
            s = fmaf(u.z, u.z, s); s = fmaf(u.w, u.w, s);
            s = fmaf(v.x, v.x, s); s = fmaf(v.y, v.y, s);
            s = fmaf(v.z, v.z, s); s = fmaf(v.w, v.w, s);
        }
        s += __shfl_xor(s, 16); s += __shfl_xor(s, 32);
        if (lane < 16) norm2L[r0 + 16 + lane] = s;
    }

    // -0.5*e2 for all codes, once
    e2L[t]       = -0.5f * e2f[t];
    e2L[512 + t] = -0.5f * e2f[512 + t];
    if (t < 256) cntL[t] = 0;
    if (t == 0) { mcount = 0; mcount2 = 0; }
    const float en2 = *enmax2;

    // per-lane swizzled LDS byte offsets for the two K-halves (loop-invariant)
    const int off0 = col * 128 + ((q       ^ (col & 7)) << 4);
    const int off1 = col * 128 + (((4 + q) ^ (col & 7)) << 4);

    f32x4 best0, best1;
    #pragma unroll
    for (int r = 0; r < 4; ++r) { best0[r] = -3.4e38f; best1[r] = -3.4e38f; }

    // 16 chunks of 16 codes over a staged quarter; KIND 0=min-track, 1=collect
#define CHUNKS(BUF, P, KIND)                                                  \
    _Pragma("unroll")                                                         \
    for (int ch = 0; ch < 16; ++ch) {                                         \
        const short8 b0 = *reinterpret_cast<const short8*>(                   \
            (char*)(BUF) + ch * 2048 + off0);                                 \
        const short8 b1 = *reinterpret_cast<const short8*>(                   \
            (char*)(BUF) + ch * 2048 + off1);                                 \
        const float e2n = e2L[(P) * 256 + ch * 16 + col];                     \
        f32x4 acc0, acc1;                                                     \
        acc0[0] = e2n; acc0[1] = e2n; acc0[2] = e2n; acc0[3] = e2n;           \
        acc1 = acc0;                                                          \
        acc0 = __builtin_amdgcn_mfma_f32_16x16x32_bf16(a0[0], b0, acc0, 0, 0, 0); \
        acc1 = __builtin_amdgcn_mfma_f32_16x16x32_bf16(a1[0], b0, acc1, 0, 0, 0); \
        acc0 = __builtin_amdgcn_mfma_f32_16x16x32_bf16(a0[1], b1, acc0, 0, 0, 0); \
        acc1 = __builtin_amdgcn_mfma_f32_16x16x32_bf16(a1[1], b1, acc1, 0, 0, 0); \
        if (KIND == 0) {                                                      \
            _Pragma("unroll")                                                 \
            for (int r = 0; r < 4; ++r) {                                     \
                best0[r] = fmaxf(best0[r], acc0[r]);                          \
                best1[r] = fmaxf(best1[r], acc1[r]);                          \
            }                                                                 \
        } else {                                                              \
            _Pragma("unroll")                                                 \
            for (int r = 0; r < 4; ++r) {                                     \
                if (acc0[r] >= best0[r]) {                                    \
                    const int rl = r0 + q * 4 + r;                            \
                    const int idx = atomicAdd(&cntL[rl], 1);                  \
                    if (idx < CAPL) candL[rl][idx] = (P) * 256 + ch * 16 + col; \
                }                                                             \
                if (acc1[r] >= best1[r]) {                                    \
                    const int rl = r0 + 16 + q * 4 + r;                       \
                    const int idx = atomicAdd(&cntL[rl], 1);                  \
                    if (idx < CAPL) candL[rl][idx] = (P) * 256 + ch * 16 + col; \
                }                                                             \
            }                                                                 \
        }                                                                     \
    }

    // ---------- sweep 1 (prefetch next quarter before computing current) ----
    __syncthreads();                       // quarter 0 resident
    STAGEQ(ebs1, 1)  CHUNKS(ebs0, 0, 0)  __syncthreads();
    STAGEQ(ebs0, 2)  CHUNKS(ebs1, 1, 0)  __syncthreads();
    STAGEQ(ebs1, 3)  CHUNKS(ebs0, 2, 0)  __syncthreads();
    CHUNKS(ebs1, 3, 0)

    // per-row max over 16 cols + acc-domain margin (dist margin / 2)
    #pragma unroll
    for (int r = 0; r < 4; ++r) {
        float v0 = best0[r], v1 = best1[r];
        v0 = fmaxf(v0, __shfl_xor(v0, 1));  v1 = fmaxf(v1, __shfl_xor(v1, 1));
        v0 = fmaxf(v0, __shfl_xor(v0, 2));  v1 = fmaxf(v1, __shfl_xor(v1, 2));
        v0 = fmaxf(v0, __shfl_xor(v0, 4));  v1 = fmaxf(v1, __shfl_xor(v1, 4));
        v0 = fmaxf(v0, __shfl_xor(v0, 8));  v1 = fmaxf(v1, __shfl_xor(v1, 8));
        const int lr = q * 4 + r;
        const float m0 = 0.0078125f * sqrtf(norm2L[r0 + lr] * en2) + 5e-5f;
        const float m1 = 0.0078125f * sqrtf(norm2L[r0 + 16 + lr] * en2) + 5e-5f;
        best0[r] = v0 - m0;               // acc-domain threshold
        best1[r] = v1 - m1;
    }

    // ---------- sweep 2: quarter 3 resident in ebs1, then 0,1,2 ----------
    STAGEQ(ebs0, 0)  CHUNKS(ebs1, 3, 1)  __syncthreads();
    STAGEQ(ebs1, 1)  CHUNKS(ebs0, 0, 1)  __syncthreads();
    STAGEQ(ebs0, 2)  CHUNKS(ebs1, 1, 1)  __syncthreads();
    CHUNKS(ebs0, 2, 1)
    __syncthreads();

    // finalize single-candidate rows (+histogram); enqueue multi/overflow rows
    int my = -1, my2 = -1, c = 0;
    if (t < 256) {
        c = cntL[t];
        if (c == 1) {
            const int code = candL[t][0];
            out_ind[rowb + t] = (float)code;
            atomicAdd(bins_i + code, 1);
        }
        else if (c <= CAPL)   my  = atomicAdd(&mcount, 1);
        else                  my2 = atomicAdd(&mcount2, 1);
    }
    __syncthreads();
    if (t == 0) { mbase = atomicAdd(gcount, mcount); mbase2 = atomicAdd(gcount2, mcount2); }
    __syncthreads();
    if (my >= 0) {
        const int row = rowb + t;
        wl[mbase + my] = row;
        cntg[row] = c;
        #pragma unroll
        for (int j = 0; j < CAPL; ++j)
            if (j < c) candg[row * CAPL + j] = candL[t][j];
    }
    if (my2 >= 0) wl2[mbase2 + my2] = rowb + t;
#undef STAGEQ
#undef CHUNKS
}

// ---- fused re-rank: thread-per-row (2..4 cands) then wave-per-row (overflow) ----
__global__ __launch_bounds__(256) void vq_rerank(
    const float* __restrict__ x, const float* __restrict__ embed,
    const float* __restrict__ e2f, const int* __restrict__ wl,
    const int* __restrict__ gcount, const int* __restrict__ cntg,
    const int* __restrict__ candg, const int* __restrict__ wl2,
    const int* __restrict__ gcount2, float* __restrict__ out_ind,
    int* __restrict__ bins_i)
{
    const int t = threadIdx.x;
    const int n = *gcount;
    for (int i = blockIdx.x * 256 + t; i < n; i += gridDim.x * 256) {
        const int row = wl[i];
        float xv[DDIM];
        {
            const float4* xp = reinterpret_cast<const float4*>(x + (size_t)row * DDIM);
            float4 xq[16];
            #pragma unroll
            for (int qq = 0; qq < 16; ++qq) xq[qq] = xp[qq];   // independent loads
            #pragma unroll
            for (int qq = 0; qq < 16; ++qq) {
                xv[qq*4+0] = xq[qq].x; xv[qq*4+1] = xq[qq].y;
                xv[qq*4+2] = xq[qq].z; xv[qq*4+3] = xq[qq].w;
            }
        }
        float x2 = 0.f;
        #pragma unroll
        for (int d = 0; d < DDIM; ++d) x2 = fmaf(xv[d], xv[d], x2);

        const int c = cntg[row];
        float bv = 3.4e38f; int bk = 0x7fffffff;
        for (int ci = 0; ci < c; ++ci) {
            const int k = candg[row * CAPL + ci];
            const float4* ep = reinterpret_cast<const float4*>(embed + (size_t)k * DDIM);
            float dot = 0.f;
            #pragma unroll
            for (int qq = 0; qq < 16; ++qq) {
                const float4 e4 = ep[qq];
                dot = fmaf(xv[qq*4+0], e4.x, dot);
                dot = fmaf(xv[qq*4+1], e4.y, dot);
                dot = fmaf(xv[qq*4+2], e4.z, dot);
                dot = fmaf(xv[qq*4+3], e4.w, dot);
            }
            const float dist = (x2 - 2.0f * dot) + e2f[k];
            if (dist < bv || (dist == bv && k < bk)) { bv = dist; bk = k; }
        }
        out_ind[row] = (float)bk;
        atomicAdd(bins_i + bk, 1);
    }

    // overflow rows: exact full scan, one wave per row
    const int lane = t & 63;
    const int gw   = (blockIdx.x * 256 + t) >> 6;
    const int nw   = (gridDim.x * 256) >> 6;
    const int n2   = *gcount2;
    for (int e = gw; e < n2; e += nw) {
        const int row = wl2[e];
        float xv[DDIM];
        {
            const float4* xp = reinterpret_cast<const float4*>(x + (size_t)row * DDIM);
            #pragma unroll
            for (int qq = 0; qq < 16; ++qq) {
                const float4 v = xp[qq];
                xv[qq*4+0] = v.x; xv[qq*4+1] = v.y; xv[qq*4+2] = v.z; xv[qq*4+3] = v.w;
            }
        }
        float x2 = 0.f;
        #pragma unroll
        for (int d = 0; d < DDIM; ++d) x2 = fmaf(xv[d], xv[d], x2);

        float bv = 3.4e38f; int bk = 0x7fffffff;
        for (int k = lane; k < KCODES; k += 64) {
            const float* er = embed + (size_t)k * DDIM;
            float dot = 0.f;
            #pragma unroll
            for (int d = 0; d < DDIM; ++d) dot = fmaf(xv[d], er[d], dot);
            const float dist = (x2 - 2.0f * dot) + e2f[k];
            if (dist < bv) { bv = dist; bk = k; }
        }
        #pragma unroll
        for (int s = 1; s < 64; s <<= 1) {
            const float ov = __shfl_xor(bv, s);
            const int   ok = __shfl_xor(bk, s);
            if (ov < bv || (ov == bv && ok < bk)) { bv = ov; bk = ok; }
        }
        if (lane == 0) { out_ind[row] = (float)bk; atomicAdd(bins_i + bk, 1); }
    }
}

// ---- exclusive prefix over bins -> cursor ----
__global__ __launch_bounds__(1024) void vq_prefix(
    const int* __restrict__ bins_i, int* __restrict__ cursor)
{
    __shared__ int s[KCODES];
    const int t = threadIdx.x;
    const int b = bins_i[t];
    s[t] = b;
    __syncthreads();
    for (int d = 1; d < KCODES; d <<= 1) {
        const int v = (t >= d) ? s[t - d] : 0;
        __syncthreads();
        s[t] += v;
        __syncthreads();
    }
    cursor[t] = s[t] - b;
}

// ---- scatter packed (code<<20)|row into code-sorted order ----
__global__ __launch_bounds__(256) void vq_scatter(
    const float* __restrict__ out_ind, int* __restrict__ cursor, int* __restrict__ sorted)
{
    const int row  = blockIdx.x * 256 + threadIdx.x;
    const int code = (int)out_ind[row];
    const int pos  = atomicAdd(cursor + code, 1);
    sorted[pos] = (code << 20) | row;
}

// ---- balanced segmented reduce: 64 positions per wave, boundary atomics ----
__global__ __launch_bounds__(256) void vq_reduce(
    const float* __restrict__ x, const int* __restrict__ sorted,
    float* __restrict__ esum)
{
    const int t = threadIdx.x, lane = t & 63, w = t >> 6;
    const int p0 = (blockIdx.x * 4 + w) * 64;     // this wave's 64 positions

    int cur = sorted[p0] >> 20;
    float acc = 0.f;
    #pragma unroll 4
    for (int i = 0; i < 64; i += 4) {
        const int4 e4 = *reinterpret_cast<const int4*>(sorted + p0 + i);
        const float v0 = x[(size_t)(e4.x & 0xFFFFF) * DDIM + lane];
        const float v1 = x[(size_t)(e4.y & 0xFFFFF) * DDIM + lane];
        const float v2 = x[(size_t)(e4.z & 0xFFFFF) * DDIM + lane];
        const float v3 = x[(size_t)(e4.w & 0xFFFFF) * DDIM + lane];
        const int c0 = e4.x >> 20, c1 = e4.y >> 20, c2 = e4.z >> 20, c3 = e4.w >> 20;
        if (c0 != cur) { unsafeAtomicAdd(esum + cur * DDIM + lane, acc); acc = 0.f; cur = c0; }
        acc += v0;
        if (c1 != cur) { unsafeAtomicAdd(esum + cur * DDIM + lane, acc); acc = 0.f; cur = c1; }
        acc += v1;
        if (c2 != cur) { unsafeAtomicAdd(esum + cur * DDIM + lane, acc); acc = 0.f; cur = c2; }
        acc += v2;
        if (c3 != cur) { unsafeAtomicAdd(esum + cur * DDIM + lane, acc); acc = 0.f; cur = c3; }
        acc += v3;
    }
    unsafeAtomicAdd(esum + cur * DDIM + lane, acc);
}

// ---- finalize: EMA + Laplace smoothing ----
__global__ __launch_bounds__(1024) void vq_finalize(
    const float* __restrict__ cluster_size, const float* __restrict__ embed_avg,
    const int* __restrict__ bins_i, float* __restrict__ out_cs,
    float* __restrict__ out_eavg, float* __restrict__ out_enorm)
{
    __shared__ float red[KCODES];
    __shared__ float css[KCODES];
    const int t = threadIdx.x;

    const float csn = cluster_size[t] * 0.1f + (float)bins_i[t] * 0.9f;
    red[t] = csn;
    __syncthreads();
    for (int s = 512; s > 0; s >>= 1) {
        if (t < s) red[t] += red[t + s];
        __syncthreads();
    }
    const float n = red[0];
    out_cs[t] = csn;
    css[t] = (csn + 1e-5f) / (n + (float)(KCODES * 1e-5)) * n;
    __syncthreads();

    #pragma unroll
    for (int i = 0; i < 16; ++i) {
        const int f4 = t + i * 1024;
        const int k  = f4 >> 4;
        const float4 ea = reinterpret_cast<const float4*>(embed_avg)[f4];
        const float4 su = reinterpret_cast<const float4*>(out_eavg)[f4];
        const float  cc = css[k];
        float4 ean, en;
        ean.x = ea.x * 0.1f + su.x * 0.9f; en.x = ean.x / cc;
        ean.y = ea.y * 0.1f + su.y * 0.9f; en.y = ean.y / cc;
        ean.z = ea.z * 0.1f + su.z * 0.9f; en.z = ean.z / cc;
        ean.w = ea.w * 0.1f + su.w * 0.9f; en.w = ean.w / cc;
        reinterpret_cast<float4*>(out_eavg)[f4]  = ean;
        reinterpret_cast<float4*>(out_enorm)[f4] = en;
    }
}

// ---- quantize gather (runs last; out_q region doubles as scratch before) ----
__global__ __launch_bounds__(256) void vq_quant(
    const float* __restrict__ out_ind, const float* __restrict__ embed,
    float* __restrict__ out_q)
{
    __shared__ int inds[256];
    const int t = threadIdx.x;
    const int row0 = blockIdx.x * 256;
    inds[t] = (int)out_ind[row0 + t];
    __syncthreads();
    #pragma unroll
    for (int i = 0; i < 16; ++i) {
        const int f = t + i * 256;
        const int r = f >> 4, dq = f & 15;
        const int code = inds[r];
        const float4 ev = *reinterpret_cast<const float4*>(
            embed + (size_t)code * DDIM + dq * 4);
        *reinterpret_cast<float4*>(out_q + (size_t)(row0 + r) * DDIM + dq * 4) = ev;
    }
}

extern "C" void kernel_launch(void* const* d_in, const int* in_sizes, int n_in,
                              void* d_out, int out_size, void* d_ws, size_t ws_size,
                              hipStream_t stream)
{
    const float* x            = (const float*)d_in[0];
    const float* embed        = (const float*)d_in[1];
    const float* cluster_size = (const float*)d_in[2];
    const float* embed_avg    = (const float*)d_in[3];

    float* out      = (float*)d_out;
    float* out_q    = out;                                   // N*D (scratch until vq_quant)
    float* out_ind  = out_q + (size_t)NROWS * DDIM;          // N
    float* out_cs   = out_ind + NROWS;                       // K
    float* out_eavg = out_cs + KCODES;                       // K*D (embed_sum accum, then EMA)
    float* out_en   = out_eavg + (size_t)KCODES * DDIM;      // K*D (eb/e2f scratch, then enorm)

    unsigned short* eb = (unsigned short*)out_en;            // K*D bf16 = 128 KB (pre-swizzled)
    float* e2f = out_en + 32768;                             // K floats

    int* S      = (int*)out_q;                               // scratch inside out_q
    int* candg  = S;                                         // N*4
    int* cntg   = S + 1048576;                               // N
    int* wl     = S + 1310720;                               // N
    int* wl2    = S + 1572864;                               // N
    int* sorted = S + 1835008;                               // N
    int* bins_i = S + 2097152;                               // K
    int* gcount = bins_i + KCODES;                           // 1
    int* gcount2= gcount + 1;                                // 1
    float* enmax2 = (float*)(gcount2 + 1);                   // 1
    int* cursor = gcount2 + 2;                               // K

    hipMemsetAsync(bins_i, 0, (KCODES + 3) * sizeof(int), stream);
    hipMemsetAsync(out_eavg, 0, (size_t)KCODES * DDIM * sizeof(float), stream);

    vq_prep    <<<KCODES / 256, 256, 0, stream>>>(embed, eb, e2f, enmax2);
    vq_phaseA  <<<NROWS / 256, 512, 0, stream>>>(x, eb, e2f, enmax2, out_ind,
                                                 candg, cntg, wl, gcount,
                                                 wl2, gcount2, bins_i);
    vq_rerank  <<<512, 256, 0, stream>>>(x, embed, e2f, wl, gcount, cntg, candg,
                                         wl2, gcount2, out_ind, bins_i);
    vq_prefix  <<<1, 1024, 0, stream>>>(bins_i, cursor);
    vq_scatter <<<NROWS / 256, 256, 0, stream>>>(out_ind, cursor, sorted);
    vq_reduce  <<<NROWS / 256, 256, 0, stream>>>(x, sorted, out_eavg);
    vq_finalize<<<1, 1024, 0, stream>>>(cluster_size, embed_avg, bins_i,
                                        out_cs, out_eavg, out_en);
    vq_quant   <<<NROWS / 256, 256, 0, stream>>>(out_ind, embed, out_q);
}